// Round 11
// baseline (105.259 us; speedup 1.0000x reference)
//
#include <hip/hip_runtime.h>
#include <math.h>

typedef _Float16 half8 __attribute__((ext_vector_type(8)));
typedef float    f32x4 __attribute__((ext_vector_type(4)));

#define TOKENS  32768
#define HIDDEN  2048
#define EXPERTS 64
#define TOPK    8
#define NSTEPS  64               // K steps of 32

// ---------------------------------------------------------------------------
// Kernel 1: split W fp32 -> fp16 hi/lo AND pre-pack into MFMA B-fragment
// order: entry id=(s*4+n)*64+l holds W[e=n*16+(l&15)][k=s*32+(l>>4)*8 .. +7].
// Main-loop W loads become lane-contiguous 16B (perfectly coalesced, one base).
// ---------------------------------------------------------------------------
__global__ void wsplit_pack(const float* __restrict__ W,
                            _Float16* __restrict__ whp, _Float16* __restrict__ wlp) {
    int id = blockIdx.x * 256 + threadIdx.x;    // 0..16383
    int s = id >> 8;
    int n = (id >> 6) & 3;
    int l = id & 63;
    int e  = n * 16 + (l & 15);
    int k0 = s * 32 + (l >> 4) * 8;
    const float* src = W + (size_t)e * HIDDEN + k0;
    float4 v0 = *(const float4*)(src);
    float4 v1 = *(const float4*)(src + 4);
    float f[8] = {v0.x, v0.y, v0.z, v0.w, v1.x, v1.y, v1.z, v1.w};
    half8 hi, lo;
    #pragma unroll
    for (int j = 0; j < 8; ++j) {
        _Float16 h = (_Float16)f[j];
        hi[j] = h;
        lo[j] = (_Float16)(f[j] - (float)h);
    }
    *(half8*)(whp + (size_t)id * 8) = hi;
    *(half8*)(wlp + (size_t)id * 8) = lo;
}

// ---------------------------------------------------------------------------
// Kernel 2: wave-autonomous MFMA router (fp16x3 split: hi*hi+hi*lo+lo*hi).
// NO LDS / NO barriers in the K-loop. Each wave: 16 tokens x 64 experts x
// full K. A-frags direct from global (lane row = l&15, k-chunk (l>>4)*8),
// 4-step rolling queue (statically indexed). W-frags from the packed L2-hot
// buffers, 2-slot queue, 1-step ahead. acc = 4 x f32x4.
// Epilogue: wave-private LDS scratch + lgkmcnt (no __syncthreads), per-token
// top-8 + softmax + scatter, coalesced writes. Indices stored as floats.
// ---------------------------------------------------------------------------
__global__ __launch_bounds__(256, 1)
void router_nb(const float* __restrict__ A,
               const _Float16* __restrict__ WhP,
               const _Float16* __restrict__ WlP,
               const float* __restrict__ bias,
               float* __restrict__ out) {
    __shared__ float lds[8704];        // 4 waves x ([16][68] logits + [16][68] scat)
    const int tid = threadIdx.x;
    const int wv  = tid >> 6;
    const int l   = tid & 63;
    const int wid = blockIdx.x * 4 + wv;
    const int t0  = wid * 16;

    const float*    pa  = A + ((size_t)(t0 + (l & 15))) * HIDDEN + (l >> 4) * 8;
    const _Float16* pwh = WhP + (size_t)l * 8;
    const _Float16* pwl = WlP + (size_t)l * 8;

    f32x4 acc[4];
    #pragma unroll
    for (int n = 0; n < 4; ++n) acc[n] = (f32x4){0.f, 0.f, 0.f, 0.f};

    float4 qa[4][2];                   // A queue: 4 steps x 2 float4
    half8  qwh[2][4], qwl[2][4];       // W queue: 2 slots x 4 expert tiles

    #pragma unroll
    for (int p = 0; p < 4; ++p) {      // A steps 0..3
        qa[p][0] = *(const float4*)(pa + p * 32);
        qa[p][1] = *(const float4*)(pa + p * 32 + 4);
    }
    #pragma unroll
    for (int n = 0; n < 4; ++n) {      // W step 0
        qwh[0][n] = *(const half8*)(pwh + (size_t)n * 512);
        qwl[0][n] = *(const half8*)(pwl + (size_t)n * 512);
    }

    #pragma unroll 1
    for (int blk = 0; blk < 16; ++blk) {
        #pragma unroll
        for (int ph = 0; ph < 4; ++ph) {          // compile-time phase
            const int s   = blk * 4 + ph;
            const int cur = ph & 1;               // == s&1
            // convert A step s -> hi/lo frags
            half8 ahi, alo;
            {
                float4 v0 = qa[ph][0], v1 = qa[ph][1];
                float f[8] = {v0.x, v0.y, v0.z, v0.w, v1.x, v1.y, v1.z, v1.w};
                #pragma unroll
                for (int j = 0; j < 8; ++j) {
                    _Float16 h = (_Float16)f[j];
                    ahi[j] = h;
                    alo[j] = (_Float16)(f[j] - (float)h);
                }
            }
            // refill A queue: step s+4 (in flight ~4 steps)
            if (s + 4 < NSTEPS) {
                qa[ph][0] = *(const float4*)(pa + (s + 4) * 32);
                qa[ph][1] = *(const float4*)(pa + (s + 4) * 32 + 4);
            }
            // prefetch W step s+1 into the other slot
            if (s + 1 < NSTEPS) {
                #pragma unroll
                for (int n = 0; n < 4; ++n) {
                    qwh[cur ^ 1][n] = *(const half8*)(pwh + ((size_t)(s + 1) * 4 + n) * 512);
                    qwl[cur ^ 1][n] = *(const half8*)(pwl + ((size_t)(s + 1) * 4 + n) * 512);
                }
            }
            // 12 MFMAs
            #pragma unroll
            for (int n = 0; n < 4; ++n) {
                acc[n] = __builtin_amdgcn_mfma_f32_16x16x32_f16(ahi, qwh[cur][n], acc[n], 0, 0, 0);
                acc[n] = __builtin_amdgcn_mfma_f32_16x16x32_f16(ahi, qwl[cur][n], acc[n], 0, 0, 0);
                acc[n] = __builtin_amdgcn_mfma_f32_16x16x32_f16(alo, qwh[cur][n], acc[n], 0, 0, 0);
            }
        }
    }

    // ---- wave-private epilogue (no __syncthreads; same-wave LDS + lgkmcnt) ----
    float* lg = lds + wv * 1088;               // [16][68] logits
    float* sp = lds + 4352 + wv * 1088;        // [16][68] scatter

    // D layout (verified r8): token row = (l>>4)*4+q, expert col = n*16+(l&15)
    #pragma unroll
    for (int n = 0; n < 4; ++n) {
        float b = bias[n * 16 + (l & 15)];
        #pragma unroll
        for (int q = 0; q < 4; ++q)
            lg[((l >> 4) * 4 + q) * 68 + n * 16 + (l & 15)] = acc[n][q] + b;
    }
    #pragma unroll
    for (int i = 0; i < 17; ++i)               // zero scat: 17*64 = 1088 exact
        sp[l + 64 * i] = 0.f;
    asm volatile("s_waitcnt lgkmcnt(0)" ::: "memory");

    if (l < 16) {
        const int t = l;
        float v[64];
        #pragma unroll
        for (int e = 0; e < 64; ++e) v[e] = lg[t * 68 + e];

        float tvals[TOPK]; int tix[TOPK]; float probs[TOPK];
        unsigned long long chosen = 0ull;
        #pragma unroll
        for (int j = 0; j < TOPK; ++j) {
            float best = -INFINITY; int bi = 0;
            #pragma unroll
            for (int e = 0; e < 64; ++e) {
                bool ok = ((chosen >> e) & 1ull) == 0ull;
                if (ok && v[e] > best) { best = v[e]; bi = e; }  // strict >: lowest idx on tie
            }
            chosen |= (1ull << bi);
            tvals[j] = best; tix[j] = bi;
        }
        float m = tvals[0];
        float ssum = 0.f;
        #pragma unroll
        for (int j = 0; j < TOPK; ++j) { probs[j] = __expf(tvals[j] - m); ssum += probs[j]; }
        float inv = 1.f / ssum;
        #pragma unroll
        for (int j = 0; j < TOPK; ++j) probs[j] *= inv;

        #pragma unroll
        for (int j = 0; j < TOPK; ++j) sp[t * 68 + tix[j]] = probs[j];

        float* oidx = out + (size_t)TOKENS * EXPERTS;
        #pragma unroll
        for (int j = 0; j < TOPK; ++j)
            oidx[(size_t)(t0 + t) * TOPK + j] = (float)tix[j];
    }
    asm volatile("s_waitcnt lgkmcnt(0)" ::: "memory");

    // coalesced score write: 16 tokens x 64 experts = 256 float4 per wave
    float* oscore = out + (size_t)wid * 1024;
    #pragma unroll
    for (int p = 0; p < 4; ++p) {
        int fi  = l + 64 * p;                  // 0..255
        int tok = fi >> 4;
        int es  = (fi & 15) * 4;
        float4 vv;
        vv.x = sp[tok * 68 + es + 0];
        vv.y = sp[tok * 68 + es + 1];
        vv.z = sp[tok * 68 + es + 2];
        vv.w = sp[tok * 68 + es + 3];
        *(float4*)(oscore + (size_t)fi * 4) = vv;
    }
}

extern "C" void kernel_launch(void* const* d_in, const int* in_sizes, int n_in,
                              void* d_out, int out_size, void* d_ws, size_t ws_size,
                              hipStream_t stream) {
    const float* A    = (const float*)d_in[0];   // [32768, 2048] fp32
    const float* W    = (const float*)d_in[1];   // [64, 2048] fp32
    const float* bias = (const float*)d_in[2];   // [64] fp32
    float* out = (float*)d_out;                  // scores (32768*64) ++ idx (32768*8)

    _Float16* whp = (_Float16*)d_ws;             // 256 KB packed hi
    _Float16* wlp = whp + EXPERTS * HIDDEN;      // 256 KB packed lo

    wsplit_pack<<<64, 256, 0, stream>>>(W, whp, wlp);
    router_nb<<<TOKENS / 64, 256, 0, stream>>>(A, whp, wlp, bias, out);
}

// Round 12
// 69.978 us; speedup vs baseline: 1.5042x; 1.5042x over previous
//
#include <hip/hip_runtime.h>
#include <math.h>

typedef _Float16 half8 __attribute__((ext_vector_type(8)));
typedef _Float16 half4 __attribute__((ext_vector_type(4)));
typedef float    f32x4 __attribute__((ext_vector_type(4)));

#define TOKENS  32768
#define HIDDEN  2048
#define EXPERTS 64
#define TOPK    8
#define BKW     64                 // k per staged window
#define NWIN    (HIDDEN / BKW)     // 32
#define LDH     72                 // LDS row stride in halves (144 B)
#define BUFH    (4 * 64 * LDH)     // halves per window buffer (Ahi|Alo|Whi|Wlo)

// ---------------------------------------------------------------------------
// Kernel 1: split W fp32 -> (Whi, Wlo) fp16, row-major [64][2048] in d_ws.
// ---------------------------------------------------------------------------
__global__ void wsplit(const float* __restrict__ W,
                       _Float16* __restrict__ whi, _Float16* __restrict__ wlo) {
    int i = blockIdx.x * 256 + threadIdx.x;     // 0..131071
    float w = W[i];
    _Float16 h = (_Float16)w;
    whi[i] = h;
    wlo[i] = (_Float16)(w - (float)h);
}

// ---------------------------------------------------------------------------
// Kernel 2: MFMA router, fp16x3 split (hi*hi + hi*lo + lo*hi, fp32 acc).
// r11 vs r8 (best, 64.8us): LDS double-buffered (2 x 36.9 KB) + two static
// register staging sets (A/B) in an unroll-by-2 loop -> loads for window s+2
// are issued BEFORE compute of window s and waited at the LDS-store at the
// END of window s+1: ~2 compute-windows of latency cover (>900cyc HBM), and
// only ONE barrier per window (r8 had 2 + a vmcnt drain each window).
// Block = 256 thr (4 waves) owns 64 tokens x 64 experts x full K.
// ---------------------------------------------------------------------------
__global__ __launch_bounds__(256, 1)
void router_db(const float* __restrict__ A,
               const _Float16* __restrict__ Wh,
               const _Float16* __restrict__ Wl,
               const float* __restrict__ bias,
               float* __restrict__ out) {
    __shared__ __align__(16) _Float16 hsm[2 * BUFH];   // 73728 B
    const int tid = threadIdx.x;
    const int w   = tid >> 6;          // wave = 16-token slab
    const int l   = tid & 63;
    const int g   = blockIdx.x;

    // staging maps
    const int s_tok = tid >> 4;        // 0..15 (rows s_tok, +16, +32, +48)
    const int s_c   = tid & 15;        // float4 chunk
    const int we    = tid >> 2;        // 0..63 expert row
    const int wc    = tid & 3;         // half8 chunks wc*8, wc*8+32

    const float*    Abase = A + (size_t)g * 64 * HIDDEN;
    const _Float16* WhB   = Wh + (size_t)we * HIDDEN;
    const _Float16* WlB   = Wl + (size_t)we * HIDDEN;

    f32x4 acc[4];
    #pragma unroll
    for (int n = 0; n < 4; ++n) acc[n] = (f32x4){0.f, 0.f, 0.f, 0.f};

    // two static staging sets (rule #20: no runtime indexing)
    float4 aA0, aA1, aA2, aA3;  half8 wAh0, wAh1, wAl0, wAl1;
    float4 aB0, aB1, aB2, aB3;  half8 wBh0, wBh1, wBl0, wBl1;

    #define LOADS(S, win) do {                                               \
        const float* p_ = Abase + (size_t)(win) * BKW + s_c * 4;             \
        a##S##0 = *(const float4*)(p_ + (size_t)(s_tok     ) * HIDDEN);      \
        a##S##1 = *(const float4*)(p_ + (size_t)(s_tok + 16) * HIDDEN);      \
        a##S##2 = *(const float4*)(p_ + (size_t)(s_tok + 32) * HIDDEN);      \
        a##S##3 = *(const float4*)(p_ + (size_t)(s_tok + 48) * HIDDEN);      \
        w##S##h0 = *(const half8*)(WhB + (win) * BKW + wc * 8);              \
        w##S##h1 = *(const half8*)(WhB + (win) * BKW + wc * 8 + 32);         \
        w##S##l0 = *(const half8*)(WlB + (win) * BKW + wc * 8);              \
        w##S##l1 = *(const half8*)(WlB + (win) * BKW + wc * 8 + 32);         \
    } while (0)

    #define CVT1(B, v, trow) do {                                            \
        _Float16 h0_ = (_Float16)(v).x, h1_ = (_Float16)(v).y;               \
        _Float16 h2_ = (_Float16)(v).z, h3_ = (_Float16)(v).w;               \
        half4 hh_ = {h0_, h1_, h2_, h3_};                                    \
        half4 ll_ = {(_Float16)((v).x - (float)h0_),                         \
                     (_Float16)((v).y - (float)h1_),                         \
                     (_Float16)((v).z - (float)h2_),                         \
                     (_Float16)((v).w - (float)h3_)};                        \
        *(half4*)(&hsm[(B) + (trow) * LDH + s_c * 4]) = hh_;                 \
        *(half4*)(&hsm[(B) + 64 * LDH + (trow) * LDH + s_c * 4]) = ll_;      \
    } while (0)

    #define STORES(S, B) do {                                                \
        CVT1(B, a##S##0, s_tok);                                             \
        CVT1(B, a##S##1, s_tok + 16);                                        \
        CVT1(B, a##S##2, s_tok + 32);                                        \
        CVT1(B, a##S##3, s_tok + 48);                                        \
        *(half8*)(&hsm[(B) + 2 * 64 * LDH + we * LDH + wc * 8])      = w##S##h0; \
        *(half8*)(&hsm[(B) + 2 * 64 * LDH + we * LDH + wc * 8 + 32]) = w##S##h1; \
        *(half8*)(&hsm[(B) + 3 * 64 * LDH + we * LDH + wc * 8])      = w##S##l0; \
        *(half8*)(&hsm[(B) + 3 * 64 * LDH + we * LDH + wc * 8 + 32]) = w##S##l1; \
    } while (0)

    #define COMPUTE(B) do {                                                  \
        _Pragma("unroll")                                                    \
        for (int ks = 0; ks < 2; ++ks) {                                     \
            const int ko = ks * 32 + (l >> 4) * 8;                           \
            half8 ahi = *(const half8*)(&hsm[(B) + (w * 16 + (l & 15)) * LDH + ko]); \
            half8 alo = *(const half8*)(&hsm[(B) + 64 * LDH + (w * 16 + (l & 15)) * LDH + ko]); \
            _Pragma("unroll")                                                \
            for (int n = 0; n < 4; ++n) {                                    \
                half8 bh = *(const half8*)(&hsm[(B) + 2 * 64 * LDH + (n * 16 + (l & 15)) * LDH + ko]); \
                half8 bl = *(const half8*)(&hsm[(B) + 3 * 64 * LDH + (n * 16 + (l & 15)) * LDH + ko]); \
                acc[n] = __builtin_amdgcn_mfma_f32_16x16x32_f16(ahi, bh, acc[n], 0, 0, 0); \
                acc[n] = __builtin_amdgcn_mfma_f32_16x16x32_f16(ahi, bl, acc[n], 0, 0, 0); \
                acc[n] = __builtin_amdgcn_mfma_f32_16x16x32_f16(alo, bh, acc[n], 0, 0, 0); \
            }                                                                \
        }                                                                    \
    } while (0)

    // ---- prologue: win0 -> buf0 (drain ok, once); issue win1 into set A ----
    LOADS(A, 0);
    STORES(A, 0);
    LOADS(A, 1);
    __syncthreads();                   // buf0 published

    // ---- main loop: 1 barrier/window, 2-window load pipeline ----
    #pragma unroll 1
    for (int s = 0; s < NWIN; s += 2) {
        if (s + 2 < NWIN) LOADS(B, s + 2);       // in flight ~2 windows
        COMPUTE(0);                              // window s from buf0
        if (s + 1 < NWIN) STORES(A, BUFH);       // win s+1 -> buf1 (vmcnt waits here)
        __syncthreads();                         // buf1 published

        if (s + 3 < NWIN) LOADS(A, s + 3);
        COMPUTE(BUFH);                           // window s+1 from buf1
        if (s + 2 < NWIN) STORES(B, 0);          // win s+2 -> buf0
        __syncthreads();                         // buf0 published
    }
    #undef LOADS
    #undef CVT1
    #undef STORES
    #undef COMPUTE

    // ---- epilogue: logits (+bias) to LDS, top-8 + softmax + scatter ----
    float* lg = (float*)hsm;                   // [64 tok][68]
    float* sc = (float*)hsm + 64 * 68;         // [64 tok][65]

    // D layout (verified r8): token row = (l>>4)*4+q, expert col = n*16+(l&15)
    #pragma unroll
    for (int n = 0; n < 4; ++n) {
        float b = bias[n * 16 + (l & 15)];
        #pragma unroll
        for (int q = 0; q < 4; ++q) {
            int trow = w * 16 + (l >> 4) * 4 + q;
            lg[trow * 68 + n * 16 + (l & 15)] = acc[n][q] + b;
        }
    }
    for (int i = tid; i < 64 * 65; i += 256) sc[i] = 0.f;
    __syncthreads();

    if (tid < 64) {
        const int t = tid;
        float v[64];
        #pragma unroll
        for (int e = 0; e < 64; ++e) v[e] = lg[t * 68 + e];

        float tvals[TOPK]; int tix[TOPK]; float probs[TOPK];
        unsigned long long chosen = 0ull;
        #pragma unroll
        for (int j = 0; j < TOPK; ++j) {
            float best = -INFINITY; int bi = 0;
            #pragma unroll
            for (int e = 0; e < 64; ++e) {
                bool ok = ((chosen >> e) & 1ull) == 0ull;
                if (ok && v[e] > best) { best = v[e]; bi = e; }  // strict >: lowest idx on tie
            }
            chosen |= (1ull << bi);
            tvals[j] = best; tix[j] = bi;
        }
        float m = tvals[0];
        float ssum = 0.f;
        #pragma unroll
        for (int j = 0; j < TOPK; ++j) { probs[j] = __expf(tvals[j] - m); ssum += probs[j]; }
        float inv = 1.f / ssum;
        #pragma unroll
        for (int j = 0; j < TOPK; ++j) probs[j] *= inv;

        #pragma unroll
        for (int j = 0; j < TOPK; ++j) sc[t * 65 + tix[j]] = probs[j];

        float* oidx = out + (size_t)TOKENS * EXPERTS;
        const int token = g * 64 + t;
        #pragma unroll
        for (int j = 0; j < TOPK; ++j) oidx[(size_t)token * TOPK + j] = (float)tix[j];
    }
    __syncthreads();

    // ---- coalesced score write: 64 tokens x 64 experts = 1024 float4 ----
    float* oscore = out + (size_t)g * 4096;
    #pragma unroll
    for (int p = 0; p < 4; ++p) {
        int fi  = tid + 256 * p;               // float4 index 0..1023
        int tok = fi >> 4;
        int es  = (fi & 15) * 4;
        float4 vv;
        vv.x = sc[tok * 65 + es + 0];
        vv.y = sc[tok * 65 + es + 1];
        vv.z = sc[tok * 65 + es + 2];
        vv.w = sc[tok * 65 + es + 3];
        *(float4*)(oscore + (size_t)fi * 4) = vv;
    }
}

extern "C" void kernel_launch(void* const* d_in, const int* in_sizes, int n_in,
                              void* d_out, int out_size, void* d_ws, size_t ws_size,
                              hipStream_t stream) {
    const float* A    = (const float*)d_in[0];   // [32768, 2048] fp32
    const float* W    = (const float*)d_in[1];   // [64, 2048] fp32
    const float* bias = (const float*)d_in[2];   // [64] fp32
    float* out = (float*)d_out;                  // scores (32768*64) ++ idx (32768*8)

    _Float16* whi = (_Float16*)d_ws;             // 256 KB
    _Float16* wlo = whi + EXPERTS * HIDDEN;      // 256 KB

    wsplit<<<512, 256, 0, stream>>>(W, whi, wlo);
    router_db<<<TOKENS / 64, 256, 0, stream>>>(A, whi, wlo, bias, out);
}

// Round 13
// 69.214 us; speedup vs baseline: 1.5208x; 1.0110x over previous
//
#include <hip/hip_runtime.h>
#include <math.h>

typedef _Float16 half8 __attribute__((ext_vector_type(8)));
typedef float    f32x4 __attribute__((ext_vector_type(4)));

#define TOKENS  32768
#define HIDDEN  2048
#define EXPERTS 64
#define TOPK    8
#define BKW     64                 // k per window
#define NWIN    (HIDDEN / BKW)     // 32
#define LDH     72                 // LDS row stride in halves (144 B)
#define WBUF    (2 * 64 * LDH)     // halves per W buffer (hi | lo)

// ---------------------------------------------------------------------------
// Kernel 1: split W fp32 -> (Whi, Wlo) fp16, row-major [64][2048] in d_ws.
// ---------------------------------------------------------------------------
__global__ void wsplit(const float* __restrict__ W,
                       _Float16* __restrict__ whi, _Float16* __restrict__ wlo) {
    int i = blockIdx.x * 256 + threadIdx.x;     // 0..131071
    float w = W[i];
    _Float16 h = (_Float16)w;
    whi[i] = h;
    wlo[i] = (_Float16)(w - (float)h);
}

// ---------------------------------------------------------------------------
// Kernel 2: hybrid-feed MFMA router (fp16x3 split: hi*hi + hi*lo + lo*hi).
// r12 vs r8/r11: A never touches LDS. Each wave owns 16 tokens; lane reads
// A[t0+(l&15)][win*64 + ks*32 + (l>>4)*8 ..+8) directly from global (already
// MFMA A-frag layout, verified r10), via a 2-window static register queue
// (~1000cyc in flight > 900cyc HBM), cvt fp32->hi/lo fp16 in-register.
// Only W goes through LDS (16KB/window, double-buffered, 1 barrier/window,
// staged from the L2-hot pre-split buffers one window ahead).
// LDS instr/window drops ~128 -> ~80 and the A stream decouples from the
// barrier -> continuous HBM streaming. Block = 256 thr = 4 waves = 64 tokens.
// ---------------------------------------------------------------------------
__global__ __launch_bounds__(256, 1)
void router_hyb(const float* __restrict__ A,
                const _Float16* __restrict__ Wh,
                const _Float16* __restrict__ Wl,
                const float* __restrict__ bias,
                float* __restrict__ out) {
    __shared__ __align__(16) _Float16 hsm[2 * WBUF];   // 36864 B
    const int tid = threadIdx.x;
    const int wv  = tid >> 6;          // wave = 16-token slab
    const int l   = tid & 63;
    const int g   = blockIdx.x;

    // W staging map: thread -> expert row we, half8 chunks wc*8, wc*8+32
    const int we = tid >> 2;
    const int wc = tid & 3;
    const _Float16* WhB = Wh + (size_t)we * HIDDEN;
    const _Float16* WlB = Wl + (size_t)we * HIDDEN;

    // A direct-load pointer: lane row (l&15) of this wave's slab, chunk (l>>4)*8
    const float* pa = A + ((size_t)(g * 64 + wv * 16 + (l & 15))) * HIDDEN + (l >> 4) * 8;

    const int ko0 = (l >> 4) * 8;      // LDS k-offset, step 0
    const int ko1 = 32 + ko0;          // step 1

    f32x4 acc[4];
    #pragma unroll
    for (int n = 0; n < 4; ++n) acc[n] = (f32x4){0.f, 0.f, 0.f, 0.f};

    // A register queue: two static window-sets (rule #20: no runtime indexing)
    float4 aA0, aA1, aA2, aA3;         // window s   : step0 (k0..7), step1 (k32..39)
    float4 aB0, aB1, aB2, aB3;         // window s+1
    half8 swh0, swh1, swl0, swl1;      // W staging regs

    #define LOADA(S, win) do {                                               \
        const float* p_ = pa + (win) * BKW;                                  \
        a##S##0 = *(const float4*)(p_);                                      \
        a##S##1 = *(const float4*)(p_ + 4);                                  \
        a##S##2 = *(const float4*)(p_ + 32);                                 \
        a##S##3 = *(const float4*)(p_ + 36);                                 \
    } while (0)

    #define LOADW(win) do {                                                  \
        swh0 = *(const half8*)(WhB + (win) * BKW + wc * 8);                  \
        swh1 = *(const half8*)(WhB + (win) * BKW + wc * 8 + 32);             \
        swl0 = *(const half8*)(WlB + (win) * BKW + wc * 8);                  \
        swl1 = *(const half8*)(WlB + (win) * BKW + wc * 8 + 32);             \
    } while (0)

    #define STOREW(B) do {                                                   \
        *(half8*)(&hsm[(B) + we * LDH + wc * 8])                = swh0;      \
        *(half8*)(&hsm[(B) + we * LDH + wc * 8 + 32])           = swh1;      \
        *(half8*)(&hsm[(B) + 64 * LDH + we * LDH + wc * 8])      = swl0;     \
        *(half8*)(&hsm[(B) + 64 * LDH + we * LDH + wc * 8 + 32]) = swl1;     \
    } while (0)

    #define CVT8(HI, LO, V0, V1) do {                                        \
        float f_[8] = {(V0).x, (V0).y, (V0).z, (V0).w,                       \
                       (V1).x, (V1).y, (V1).z, (V1).w};                      \
        _Pragma("unroll")                                                    \
        for (int j_ = 0; j_ < 8; ++j_) {                                     \
            _Float16 h_ = (_Float16)f_[j_];                                  \
            (HI)[j_] = h_;                                                   \
            (LO)[j_] = (_Float16)(f_[j_] - (float)h_);                       \
        }                                                                    \
    } while (0)

    #define MFMA_STEP(B, AH, AL, KO) do {                                    \
        _Pragma("unroll")                                                    \
        for (int n = 0; n < 4; ++n) {                                        \
            half8 bh = *(const half8*)(&hsm[(B) + (n * 16 + (l & 15)) * LDH + (KO)]); \
            half8 bl = *(const half8*)(&hsm[(B) + 64 * LDH + (n * 16 + (l & 15)) * LDH + (KO)]); \
            acc[n] = __builtin_amdgcn_mfma_f32_16x16x32_f16(AH, bh, acc[n], 0, 0, 0); \
            acc[n] = __builtin_amdgcn_mfma_f32_16x16x32_f16(AH, bl, acc[n], 0, 0, 0); \
            acc[n] = __builtin_amdgcn_mfma_f32_16x16x32_f16(AL, bh, acc[n], 0, 0, 0); \
        }                                                                    \
    } while (0)

    #define PHASE(B, S, win) do {                                            \
        half8 ahi0, alo0, ahi1, alo1;                                        \
        CVT8(ahi0, alo0, a##S##0, a##S##1);                                  \
        CVT8(ahi1, alo1, a##S##2, a##S##3);                                  \
        if ((win) + 2 < NWIN) LOADA(S, (win) + 2);  /* refill: 2 windows out */ \
        MFMA_STEP(B, ahi0, alo0, ko0);                                       \
        MFMA_STEP(B, ahi1, alo1, ko1);                                       \
    } while (0)

    // ---- prologue ----
    LOADA(A, 0);
    LOADA(B, 1);
    LOADW(0);
    STOREW(0);
    __syncthreads();                   // buf0 ready

    // ---- main loop: 1 barrier per window ----
    #pragma unroll 1
    for (int s = 0; s < NWIN; s += 2) {
        if (s + 1 < NWIN) LOADW(s + 1);          // W next window, in flight over compute
        PHASE(0, A, s);                          // window s from buf0
        if (s + 1 < NWIN) STOREW(WBUF);
        __syncthreads();                         // buf1 ready

        if (s + 2 < NWIN) LOADW(s + 2);
        PHASE(WBUF, B, s + 1);                   // window s+1 from buf1
        if (s + 2 < NWIN) STOREW(0);
        __syncthreads();                         // buf0 ready
    }
    #undef LOADA
    #undef LOADW
    #undef STOREW
    #undef CVT8
    #undef MFMA_STEP
    #undef PHASE

    // ---- epilogue: logits (+bias) to LDS, top-8 + softmax + scatter ----
    float* lg = (float*)hsm;                   // [64 tok][68]
    float* sc = (float*)hsm + 64 * 68;         // [64 tok][65]

    // D layout (verified r8): token row = (l>>4)*4+q, expert col = n*16+(l&15)
    #pragma unroll
    for (int n = 0; n < 4; ++n) {
        float b = bias[n * 16 + (l & 15)];
        #pragma unroll
        for (int q = 0; q < 4; ++q) {
            int trow = wv * 16 + (l >> 4) * 4 + q;
            lg[trow * 68 + n * 16 + (l & 15)] = acc[n][q] + b;
        }
    }
    for (int i = tid; i < 64 * 65; i += 256) sc[i] = 0.f;
    __syncthreads();

    if (tid < 64) {
        const int t = tid;
        float v[64];
        #pragma unroll
        for (int e = 0; e < 64; ++e) v[e] = lg[t * 68 + e];

        float tvals[TOPK]; int tix[TOPK]; float probs[TOPK];
        unsigned long long chosen = 0ull;
        #pragma unroll
        for (int j = 0; j < TOPK; ++j) {
            float best = -INFINITY; int bi = 0;
            #pragma unroll
            for (int e = 0; e < 64; ++e) {
                bool ok = ((chosen >> e) & 1ull) == 0ull;
                if (ok && v[e] > best) { best = v[e]; bi = e; }  // strict >: lowest idx on tie
            }
            chosen |= (1ull << bi);
            tvals[j] = best; tix[j] = bi;
        }
        float m = tvals[0];
        float ssum = 0.f;
        #pragma unroll
        for (int j = 0; j < TOPK; ++j) { probs[j] = __expf(tvals[j] - m); ssum += probs[j]; }
        float inv = 1.f / ssum;
        #pragma unroll
        for (int j = 0; j < TOPK; ++j) probs[j] *= inv;

        #pragma unroll
        for (int j = 0; j < TOPK; ++j) sc[t * 65 + tix[j]] = probs[j];

        float* oidx = out + (size_t)TOKENS * EXPERTS;
        const int token = g * 64 + t;
        #pragma unroll
        for (int j = 0; j < TOPK; ++j) oidx[(size_t)token * TOPK + j] = (float)tix[j];
    }
    __syncthreads();

    // ---- coalesced score write: 64 tokens x 64 experts = 1024 float4 ----
    float* oscore = out + (size_t)g * 4096;
    #pragma unroll
    for (int p = 0; p < 4; ++p) {
        int fi  = tid + 256 * p;               // float4 index 0..1023
        int tok = fi >> 4;
        int es  = (fi & 15) * 4;
        float4 vv;
        vv.x = sc[tok * 65 + es + 0];
        vv.y = sc[tok * 65 + es + 1];
        vv.z = sc[tok * 65 + es + 2];
        vv.w = sc[tok * 65 + es + 3];
        *(float4*)(oscore + (size_t)fi * 4) = vv;
    }
}

extern "C" void kernel_launch(void* const* d_in, const int* in_sizes, int n_in,
                              void* d_out, int out_size, void* d_ws, size_t ws_size,
                              hipStream_t stream) {
    const float* A    = (const float*)d_in[0];   // [32768, 2048] fp32
    const float* W    = (const float*)d_in[1];   // [64, 2048] fp32
    const float* bias = (const float*)d_in[2];   // [64] fp32
    float* out = (float*)d_out;                  // scores (32768*64) ++ idx (32768*8)

    _Float16* whi = (_Float16*)d_ws;             // 256 KB
    _Float16* wlo = whi + EXPERTS * HIDDEN;      // 256 KB

    wsplit<<<512, 256, 0, stream>>>(W, whi, wlo);
    router_hyb<<<TOKENS / 64, 256, 0, stream>>>(A, whi, wlo, bias, out);
}